// Round 7
// baseline (73.814 us; speedup 1.0000x reference)
//
#include <hip/hip_runtime.h>

// PSANet 'distribute':
// out[n, h*W + w, i, j] = x[n, (i-h+63)*127 + (j-w+63), h, w], N=2, H=W=64.
//
// R7: write-granularity test at FULL occupancy.
// Block = (n, h, i0..i0+3): 1024 threads, 64 KiB LDS -> 2 blocks/CU
// = 2048 threads/CU (full). Each store instruction writes 1 KB dense
// (one (h,w) plane's 4-i chunk, 64 lanes x float4); XCD-contiguous
// neighbor blocks (same h, next i-chunk) write the adjacent 1 KB.
// Reads: 4 band slabs (di = i0..i0+3 - h + 63), predicated float4,
// line-optimal fetch (~199 MB) -- read grouping proven null (R6).
// LDS scatter banks 2-way (free); store-side ds_read_b128 dense.

#define PSA_H 64
#define PSA_W 64
#define PSA_HM 127
#define PSA_WM 127
#define PSA_HW (PSA_H * PSA_W)      // 4096
#define PSA_CHW (PSA_HM * PSA_WM)   // 16129
#define NI 4                        // i's per block

__global__ __launch_bounds__(1024) void psa_distribute_kernel(
    const float* __restrict__ in, float* __restrict__ out) {
    __shared__ float lds[NI * PSA_HW];  // 64 KiB: lds[p][w][j]

    const int b   = blockIdx.x;          // 2048 blocks
    const int xcd = b & 7;
    const int s   = (xcd << 8) + (b >> 3);   // contiguous 256-range per XCD
    const int n   = s >> 10;
    const int r   = s & 1023;
    const int h   = r >> 4;
    const int i0  = (r & 15) << 2;       // i-chunk of 4

    size_t in_base[NI];
#pragma unroll
    for (int p = 0; p < NI; ++p) {
        const int di = i0 + p - h + (PSA_H - 1);   // in [0,126]
        in_base[p] = ((size_t)n * PSA_CHW + (size_t)di * PSA_WM) * PSA_HW
                     + (size_t)h * PSA_W;
    }

    const int t     = threadIdx.x;       // 0..1023
    const int wl    = t & 15;            // float4 column
    const int djo   = (t >> 4) & 3;      // dj sub-offset
    const int wv    = t >> 6;            // wave 0..15
    const int wbase = wl << 2;

#pragma unroll
    for (int it = 0; it < 2; ++it) {
        const int dj = it * 64 + wv * 4 + djo;     // 0..127 (127 masked)
        // valid w range for this dj: [63-dj, 126-dj] clipped to [0,63]
        const bool row_ok = (dj < PSA_WM) &&
                            (wbase + 3 >= PSA_W - 1 - dj) &&
                            (wbase <= 2 * (PSA_W - 1) - dj);
        if (row_ok) {
            const int jb = dj + wbase - (PSA_W - 1);
#pragma unroll
            for (int p = 0; p < NI; ++p) {
                const float4 v = *(const float4*)(
                    in + in_base[p] + (size_t)dj * PSA_HW + wbase);
#pragma unroll
                for (int e = 0; e < 4; ++e) {
                    const int j = jb + e;
                    if ((unsigned)j < (unsigned)PSA_W) {
                        lds[p * PSA_HW + (wbase + e) * PSA_W + j] =
                            ((const float*)&v)[e];
                    }
                }
            }
        }
    }
    __syncthreads();

    // Store: per (h,w) plane, the 4-i chunk [i0*64, i0*64+256) is 1 KB
    // contiguous. One wave instruction = 64 lanes x float4 = exactly that.
    // float4 base of plane w: (n*4096 + h*64 + w)*1024 + i0*16
    const size_t out4_base0 =
        ((size_t)n * PSA_HW + (size_t)h * PSA_W) * (PSA_HW / 4)
        + (size_t)i0 * 16;

    const float4* lds4 = (const float4*)lds;
#pragma unroll
    for (int it = 0; it < 4; ++it) {
        const int idx = it * 1024 + t;   // 0..4095
        const int w   = idx >> 6;        // plane
        const int l   = idx & 63;        // p*16 + j4
        const int p   = l >> 4;
        const int j4  = l & 15;
        float4* dst = (float4*)out + out4_base0 + (size_t)w * (PSA_HW / 4);
        dst[l] = lds4[p * (PSA_HW / 4) + w * 16 + j4];
    }
}

extern "C" void kernel_launch(void* const* d_in, const int* in_sizes, int n_in,
                              void* d_out, int out_size, void* d_ws, size_t ws_size,
                              hipStream_t stream) {
    const float* x = (const float*)d_in[0];
    float* out = (float*)d_out;
    const int nblocks = 2 * PSA_H * PSA_H / NI;  // 2048
    psa_distribute_kernel<<<nblocks, 1024, 0, stream>>>(x, out);
}

// Round 8
// 70.068 us; speedup vs baseline: 1.0535x; 1.0535x over previous
//
#include <hip/hip_runtime.h>

// PSANet 'distribute':
// out[n, h*W + w, i, j] = x[n, (i-h+H-1)*(2W-1) + (j-w+W-1), h, w]
// N=2, H=W=64, HM=WM=127.
//
// FINAL (revert to R4, the best measured config: 70.4 us, 4.73 TB/s).
// Pure permutation, output-driven. Block = one (n, h, i); di = i-h+63 fixed.
// Load: float4 per lane, predicated to the valid band (line-optimal fetch,
//       ~199 MB = hard floor: only 25% of input is ever used, 67% of each
//       touched 128B line). LDS scatter banks 2-way (free).
// Store: float4 LDS reads + dense float4 global stores (134 MB exact).
// Block ordering: XCD-aware swizzle; finer locality levers measured null
// (R3/R6/R7), occupancy is the only sensitive axis (R5: -16% at 2 blk/CU).

#define PSA_H 64
#define PSA_W 64
#define PSA_HM 127
#define PSA_WM 127
#define PSA_HW (PSA_H * PSA_W)      // 4096
#define PSA_CHW (PSA_HM * PSA_WM)   // 16129

__global__ __launch_bounds__(256) void psa_distribute_kernel(
    const float* __restrict__ in, float* __restrict__ out) {
    __shared__ float lds[PSA_W * PSA_W];  // lds[w][j], 16 KiB

    const int b = blockIdx.x;
    // XCD-contiguous swizzle: grid 8192, 8 XCDs, round-robin dispatch
    const int xcd = b & 7;
    const int k   = b >> 3;              // 0..1023
    const int s   = (xcd << 10) + k;     // swizzled linear id
    const int n   = s >> 12;
    const int r   = s & 4095;            // (h,i) space
    const int t   = r >> 8;              // 16 tiles (4x4) of 16x16
    const int q   = r & 255;
    const int h   = ((t >> 2) << 4) + (q >> 4);
    const int i   = ((t & 3) << 4) + (q & 15);
    const int di  = i - h + (PSA_H - 1);   // in [0, 126]

    // element offset of (dj=0, w=0) in this block's slab
    const size_t in_base =
        ((size_t)n * PSA_CHW + (size_t)di * PSA_WM) * (size_t)PSA_HW
        + (size_t)h * PSA_W;

    const int lane = threadIdx.x & 63;
    const int wv   = threadIdx.x >> 6;   // wave id 0..3
    const int rr   = lane >> 4;          // row within 4-row group
    const int wl   = lane & 15;          // float4 column
    const int wbase = wl << 2;           // w of element 0 of this lane's float4

    // 127 rows in 32 groups of 4; wave wv takes groups g = wv, wv+4, ...
#pragma unroll
    for (int g4 = 0; g4 < 8; ++g4) {
        const int g  = g4 * 4 + wv;
        const int dj = g * 4 + rr;                 // 0..127 (127 masked)
        // valid w range: [max(0,63-dj), min(63,126-dj)]
        const bool active = (dj < PSA_WM) &&
                            (wbase + 3 >= PSA_W - 1 - dj) &&
                            (wbase <= 2 * (PSA_W - 1) - dj);
        if (active) {
            const float4 v =
                *(const float4*)(in + in_base + (size_t)dj * PSA_HW + wbase);
            const int jb = dj + wbase - (PSA_W - 1);
#pragma unroll
            for (int e = 0; e < 4; ++e) {
                const int j = jb + e;
                if ((unsigned)j < (unsigned)PSA_W) {
                    lds[(wbase + e) * PSA_W + j] = ((const float*)&v)[e];
                }
            }
        }
    }
    __syncthreads();

    // Store phase: out flat = (n*4096 + h*64 + w)*4096 + i*64 + j
    const size_t out_base =
        ((size_t)(n * PSA_HW) + (size_t)h * PSA_W) * (size_t)PSA_HW
        + (size_t)i * PSA_W;

    const float4* lds4 = (const float4*)lds;
    float4* out4 = (float4*)(out + out_base);  // out_base % 64 == 0
    const int tt = threadIdx.x;
#pragma unroll
    for (int kk = 0; kk < 4; ++kk) {
        const int id = kk * 256 + tt;    // float4 id, 0..1023
        const int w  = id >> 4;          // 16 float4 per w-row
        const int j4 = id & 15;
        out4[w * (PSA_HW / 4) + j4] = lds4[id];
    }
}

extern "C" void kernel_launch(void* const* d_in, const int* in_sizes, int n_in,
                              void* d_out, int out_size, void* d_ws, size_t ws_size,
                              hipStream_t stream) {
    const float* x = (const float*)d_in[0];
    float* out = (float*)d_out;
    const int nblocks = 2 * PSA_H * PSA_H;  // 8192
    psa_distribute_kernel<<<nblocks, 256, 0, stream>>>(x, out);
}